// Round 1
// baseline (720.208 us; speedup 1.0000x reference)
//
#include <hip/hip_runtime.h>
#include <cmath>

#define BATCH 1024
#define SOUT 36336
#define POUT 10596
#define PS_COLS 10464   // s params compacted (dec2 block removed)
#define PP_COLS 10596

__device__ __forceinline__ float sigmoidf_(float x){ return 1.0f/(1.0f+expf(-x)); }
__device__ __forceinline__ float reluf_(float x){ return x>0.0f?x:0.0f; }

// ---------------- K1: backbone hidden h2 (s and p) ----------------
__global__ __launch_bounds__(128) void k_backbone(
    const float* __restrict__ z,
    const float* __restrict__ sw1, const float* __restrict__ sb1,
    const float* __restrict__ sw2, const float* __restrict__ sb2,
    const float* __restrict__ pw1, const float* __restrict__ pb1,
    const float* __restrict__ pw2, const float* __restrict__ pb2,
    float* __restrict__ h2s, float* __restrict__ h2p)
{
  __shared__ float zsh[32];
  __shared__ float h1sh[2][64];
  const int b = blockIdx.x;
  const int tid = threadIdx.x;
  const int g = tid >> 6, o = tid & 63;
  if (tid < 32) zsh[tid] = z[b*32 + tid];
  __syncthreads();
  const float* w1 = g ? pw1 : sw1;
  const float* b1 = g ? pb1 : sb1;
  float acc = b1[o];
  #pragma unroll
  for (int i=0;i<32;i++) acc += zsh[i]*w1[i*64+o];
  h1sh[g][o] = reluf_(acc);
  __syncthreads();
  const float* w2 = g ? pw2 : sw2;
  const float* b2 = g ? pb2 : sb2;
  float acc2 = b2[o];
  #pragma unroll
  for (int i=0;i<64;i++) acc2 += h1sh[g][i]*w2[i*64+o];
  (g ? h2p : h2s)[b*64+o] = reluf_(acc2);
}

// ---------------- K2: params = h2 @ w3 + b3 (with column remap) ----------------
__global__ __launch_bounds__(256) void k_params(
    const float* __restrict__ h2, const float* __restrict__ w3,
    const float* __restrict__ b3, float* __restrict__ outp,
    int OC, int mapThresh, int mapOff, int srcStride)
{
  __shared__ float wt[64][65];
  __shared__ float h2t[32][64];
  __shared__ float bsh[64];
  const int c0 = blockIdx.x*64, b0 = blockIdx.y*32;
  const int tid = threadIdx.x;
  for (int idx=tid; idx<4096; idx+=256){
    int j = idx >> 6, cc = idx & 63;
    int c = c0 + cc;
    int src = (c < mapThresh) ? c : c + mapOff;
    wt[j][cc] = (c < OC) ? w3[(size_t)j*srcStride + src] : 0.0f;
  }
  if (tid < 64){
    int c = c0 + tid;
    int src = (c < mapThresh) ? c : c + mapOff;
    bsh[tid] = (c < OC) ? b3[src] : 0.0f;
  }
  for (int idx=tid; idx<2048; idx+=256){
    int bb = idx >> 6, j = idx & 63;
    h2t[bb][j] = h2[(size_t)(b0+bb)*64 + j];
  }
  __syncthreads();
  const int cc = tid & 63, bq = tid >> 6;
  const int c = c0 + cc;
  if (c < OC){
    for (int s=0;s<8;s++){
      int bb = bq*8 + s;
      float acc = bsh[cc];
      #pragma unroll
      for (int j=0;j<64;j++) acc += h2t[bb][j]*wt[j][cc];
      outp[(size_t)(b0+bb)*OC + c] = acc;
    }
  }
}

// ---------------- K3: 20 sequential hyper-GRU step pairs ----------------
// One block per batch element. Group 0 (tid<128) = s network, group 1 = p network.
// Per-batch params cached in dynamic LDS.
// s-compact layout: enc1 W[0,2048) b[2048,2080) | enc2 W[2080,3104) b[3104,3136)
//                   dec1 W[3136,4160) b[4160,4192) | rnn k@4192 rk@7264 b@10336 | z0init@10432
// p (reference layout): same enc/dec1 offsets, dec2 W@4192(128) b@4320(4),
//                   rnn k@4324 rk@7396 b@10468 | za0init@10564
__global__ __launch_bounds__(256) void k_seq(
    const float* __restrict__ Ps, const float* __restrict__ Pp,
    float* __restrict__ Dout, float* __restrict__ Aout)
{
  extern __shared__ float lds[];
  float* Psh = lds;                      // 10464
  float* Pph = lds + PS_COLS;            // 10596
  float* st  = lds + PS_COLS + PP_COLS;
  float* ssA = st;        // [2][32] GRU states (s,p)
  float* ztA = st + 64;   // [64] top-level (z0|za0)
  float* ziA = st + 128;  // [64] inner-level
  float* e1A = st + 192;  // [2][32]
  float* e2A = st + 256;  // [2][32]
  float* gxA = st + 320;  // [2][96]
  float* ghA = st + 512;  // [2][64]
  float* zgA = st + 640;  // [2][32]
  float* rhA = st + 704;  // [2][32]
  float* d1A = st + 768;  // [2][32]

  const int b = blockIdx.x;
  const int tid = threadIdx.x;
  const int g = tid >> 7, lt = tid & 127;

  {
    const float4* s4 = reinterpret_cast<const float4*>(Ps + (size_t)b*PS_COLS);
    float4* t4 = reinterpret_cast<float4*>(Psh);
    for (int i=tid; i<PS_COLS/4; i+=256) t4[i] = s4[i];
    const float4* p4 = reinterpret_cast<const float4*>(Pp + (size_t)b*PP_COLS);
    float4* u4 = reinterpret_cast<float4*>(Pph);
    for (int i=tid; i<PP_COLS/4; i+=256) u4[i] = p4[i];
  }
  if (tid < 64) ssA[tid] = 0.0f;
  __syncthreads();
  if (tid < 32) ztA[tid] = Psh[10432 + tid];
  else if (tid < 64) ztA[tid] = Pph[10564 + (tid - 32)];
  __syncthreads();

  const float* P = g ? Pph : Psh;
  const int RNN = g ? 4324 : 4192;
  float* e1 = e1A + g*32; float* e2 = e2A + g*32;
  float* gx = gxA + g*96; float* gh = ghA + g*64;
  float* zg = zgA + g*32; float* rh = rhA + g*32;
  float* hs = ssA + g*32; float* d1 = d1A + g*32;

  auto substep = [&](const float* xv, int aidx, int t16){
    // A: e1 = relu(xv @ Wenc1 + b)   (xv is 64-wide concat)
    if (lt < 32){
      float a0=0,a1=0,a2=0,a3=0;
      #pragma unroll
      for (int i=0;i<64;i+=4){
        a0 += xv[i+0]*P[(i+0)*32+lt];
        a1 += xv[i+1]*P[(i+1)*32+lt];
        a2 += xv[i+2]*P[(i+2)*32+lt];
        a3 += xv[i+3]*P[(i+3)*32+lt];
      }
      e1[lt] = reluf_(a0+a1+a2+a3 + P[2048+lt]);
    }
    __syncthreads();
    // B: e2 = e1 @ Wenc2 + b (no relu)
    if (lt < 32){
      float a0=0,a1=0,a2=0,a3=0;
      #pragma unroll
      for (int i=0;i<32;i+=4){
        a0 += e1[i+0]*P[2080+(i+0)*32+lt];
        a1 += e1[i+1]*P[2080+(i+1)*32+lt];
        a2 += e1[i+2]*P[2080+(i+2)*32+lt];
        a3 += e1[i+3]*P[2080+(i+3)*32+lt];
      }
      e2[lt] = a0+a1+a2+a3 + P[3104+lt];
    }
    __syncthreads();
    // C: gx[96] = e2@k + b ; gh[64] = h@rk[:, :64]
    if (lt < 96){
      float a0=0,a1=0;
      #pragma unroll
      for (int i=0;i<32;i+=2){
        a0 += e2[i+0]*P[RNN+(i+0)*96+lt];
        a1 += e2[i+1]*P[RNN+(i+1)*96+lt];
      }
      gx[lt] = a0+a1 + P[RNN+6144+lt];
    } else {
      const int o = lt - 96;
      float s0=0, s1=0;
      #pragma unroll
      for (int i=0;i<32;i++){
        float h = hs[i];
        s0 += h*P[RNN+3072+i*96+o];
        s1 += h*P[RNN+3072+i*96+o+32];
      }
      gh[o] = s0; gh[o+32] = s1;
    }
    __syncthreads();
    // D: gates
    if (lt < 32){
      zg[lt] = sigmoidf_(gx[lt] + gh[lt]);
    } else if (lt < 64){
      int o = lt - 32;
      float rg = sigmoidf_(gx[32+o] + gh[32+o]);
      rh[o] = rg * hs[o];
    }
    __syncthreads();
    // E: h' = z*h + (1-z)*tanh(xh + (r*h)@rk[:,64:])
    if (lt < 32){
      float a0=0,a1=0;
      #pragma unroll
      for (int i=0;i<32;i+=2){
        a0 += rh[i+0]*P[RNN+3072+(i+0)*96+64+lt];
        a1 += rh[i+1]*P[RNN+3072+(i+1)*96+64+lt];
      }
      float hh = tanhf(gx[64+lt] + a0+a1);
      float zv = zg[lt];
      hs[lt] = zv*hs[lt] + (1.0f - zv)*hh;
    }
    __syncthreads();
    // F: dec1 (s only when t16>=0; p always)
    const bool needDec = (g==1) || (t16 >= 0);
    if (needDec && lt < 32){
      float a0=0,a1=0;
      #pragma unroll
      for (int i=0;i<32;i+=2){
        a0 += hs[i+0]*P[3136+(i+0)*32+lt];
        a1 += hs[i+1]*P[3136+(i+1)*32+lt];
      }
      float d = reluf_(a0+a1 + P[4160+lt]);
      if (g == 0) Dout[((size_t)t16*BATCH + b)*32 + lt] = d;
      else d1[lt] = d;
    }
    __syncthreads();
    // G: p dec2 -> a (4 outputs)
    if (g == 1 && lt < 4){
      float s = P[4320+lt];
      #pragma unroll
      for (int i=0;i<32;i++) s += d1[i]*P[4192+i*4+lt];
      Aout[((size_t)aidx*BATCH + b)*4 + lt] = s;
    }
    __syncthreads();
  };

  for (int t=0;t<4;t++){
    substep(ztA, t, -1);
    if (tid < 64) ztA[tid] = ssA[tid];                       // (z0,za0) <- (new ss, new sp)
    else if (tid < 96) ziA[tid-64] = Psh[10432 + (tid-64)];  // inner restart from inits
    else if (tid < 128) ziA[tid-64] = Pph[10564 + (tid-96)];
    __syncthreads();
    for (int k=0;k<4;k++){
      substep(ziA, 4 + t*4 + k, t*4 + k);
      if (tid < 64) ziA[tid] = ssA[tid];
      __syncthreads();
    }
  }
}

// ---------------- K4: fused dec2 hypernet apply: xhat[16][B][784] ----------------
// xhat[t,b,o] = sum_i Da[t,b,i] * (sum_j h2s[b,j]*w3[j,c(i,o)] + b3[c(i,o)])
// with Da[...,32]=1 pairing with the dec2 bias columns.
__global__ __launch_bounds__(256) void k_xhat(
    const float* __restrict__ h2s, const float* __restrict__ Dm,
    const float* __restrict__ w3, const float* __restrict__ b3,
    float* __restrict__ XH)
{
  __shared__ float h2a[8][64];
  __shared__ float Da[16][8][33];
  __shared__ float wt[64][32];
  __shared__ float bsh[32];
  const int o0 = blockIdx.x*32, b0 = blockIdx.y*8;
  const int tid = threadIdx.x;
  const int bl = tid >> 5, ol = tid & 31;
  for (int idx=tid; idx<512; idx+=256)
    h2a[idx>>6][idx&63] = h2s[(size_t)(b0 + (idx>>6))*64 + (idx&63)];
  for (int idx=tid; idx<4096; idx+=256){
    int t = idx >> 8, rem = idx & 255;
    int bb = rem >> 5, i = rem & 31;
    Da[t][bb][i] = Dm[((size_t)t*BATCH + b0+bb)*32 + i];
  }
  if (tid < 128) Da[tid>>3][tid&7][32] = 1.0f;
  __syncthreads();
  float acc[16];
  #pragma unroll
  for (int t=0;t<16;t++) acc[t]=0.0f;
  for (int i=0;i<33;i++){
    const int cbase = (i<32) ? (4192 + i*784) : 29280;
    for (int idx=tid; idx<2048; idx+=256){
      int j = idx >> 5, oo = idx & 31;
      int o = o0 + oo;
      wt[j][oo] = (o < 784) ? w3[(size_t)j*SOUT + cbase + o] : 0.0f;
    }
    if (tid < 32){
      int o = o0 + tid;
      bsh[tid] = (o < 784) ? b3[cbase + o] : 0.0f;
    }
    __syncthreads();
    float V = bsh[ol];
    #pragma unroll
    for (int j=0;j<64;j++) V += h2a[bl][j]*wt[j][ol];
    #pragma unroll
    for (int t=0;t<16;t++) acc[t] += Da[t][bl][i]*V;
    __syncthreads();
  }
  const int o = o0 + ol;
  if (o < 784){
    #pragma unroll
    for (int t=0;t<16;t++)
      XH[((size_t)t*BATCH + b0+bl)*784 + o] = acc[t];
  }
}

// ---------------- bilinear forward sampler ----------------
__device__ __forceinline__ float fetchpix(const float* __restrict__ img, int y, int x){
  if ((unsigned)y >= 28u || (unsigned)x >= 28u) return 0.0f;
  return img[y*28 + x];
}
__device__ __forceinline__ float bilin(const float* __restrict__ img,
                                       float a0, float a1, float a2, float a3,
                                       int r, int c){
  const float stepv = 2.0f/27.0f;
  float gxv = -1.0f + stepv*(float)c;
  float gyv = -1.0f + stepv*(float)r;
  float srcx = (a0 + 1.0f)*gxv + a2;
  float srcy = (a1 + 1.0f)*gyv + a3;
  float px = (srcx + 1.0f)*13.5f;
  float py = (srcy + 1.0f)*13.5f;
  float x0f = floorf(px), y0f = floorf(py);
  float wx = px - x0f, wy = py - y0f;
  int x0 = (int)x0f, y0 = (int)y0f;
  float v00 = fetchpix(img, y0,   x0);
  float v01 = fetchpix(img, y0,   x0+1);
  float v10 = fetchpix(img, y0+1, x0);
  float v11 = fetchpix(img, y0+1, x0+1);
  return v00*(1.0f-wx)*(1.0f-wy) + v01*wx*(1.0f-wy)
       + v10*(1.0f-wx)*wy + v11*wx*wy;
}

// ---------------- K5: level-0 composite out0[4][B][784] ----------------
__global__ __launch_bounds__(256) void k_out0(
    const float* __restrict__ XH, const float* __restrict__ Am,
    float* __restrict__ O0)
{
  int idx = blockIdx.x*256 + threadIdx.x;
  if (idx >= 4*BATCH*784) return;
  int pix = idx % 784;
  int b = (idx / 784) & (BATCH-1);
  int t = idx / (784*BATCH);
  int r = pix / 28, c = pix % 28;
  float acc = 0.0f;
  #pragma unroll
  for (int k=0;k<4;k++){
    const float* ap = Am + ((size_t)(4 + t*4 + k)*BATCH + b)*4;
    const float* img = XH + ((size_t)(t*4 + k)*BATCH + b)*784;
    acc += bilin(img, ap[0], ap[1], ap[2], ap[3], r, c);
  }
  O0[((size_t)t*BATCH + b)*784 + pix] = acc;
}

// ---------------- K6: level-1 composite -> d_out ----------------
__global__ __launch_bounds__(256) void k_final(
    const float* __restrict__ O0, const float* __restrict__ Am,
    float* __restrict__ outp)
{
  int idx = blockIdx.x*256 + threadIdx.x;
  if (idx >= BATCH*784) return;
  int pix = idx % 784, b = idx / 784;
  int r = pix / 28, c = pix % 28;
  float acc = 0.0f;
  #pragma unroll
  for (int t=0;t<4;t++){
    const float* ap = Am + ((size_t)t*BATCH + b)*4;
    acc += bilin(O0 + ((size_t)t*BATCH + b)*784, ap[0], ap[1], ap[2], ap[3], r, c);
  }
  outp[idx] = acc;
}

extern "C" void kernel_launch(void* const* d_in, const int* in_sizes, int n_in,
                              void* d_out, int out_size, void* d_ws, size_t ws_size,
                              hipStream_t stream)
{
  // inputs: x(unused), z, s_w1,s_b1,s_w2,s_b2,s_w3,s_b3, p_w1,p_b1,p_w2,p_b2,p_w3,p_b3
  const float* z   = (const float*)d_in[1];
  const float* sw1 = (const float*)d_in[2];
  const float* sb1 = (const float*)d_in[3];
  const float* sw2 = (const float*)d_in[4];
  const float* sb2 = (const float*)d_in[5];
  const float* sw3 = (const float*)d_in[6];
  const float* sb3 = (const float*)d_in[7];
  const float* pw1 = (const float*)d_in[8];
  const float* pb1 = (const float*)d_in[9];
  const float* pw2 = (const float*)d_in[10];
  const float* pb2 = (const float*)d_in[11];
  const float* pw3 = (const float*)d_in[12];
  const float* pb3 = (const float*)d_in[13];

  float* ws  = (float*)d_ws;
  float* h2s = ws + 0;          // 65536
  float* h2p = ws + 65536;      // 65536
  float* Ps  = ws + 131072;     // 1024*10464
  float* Pp  = ws + 10846208;   // 1024*10596
  float* Dm  = ws + 21696512;   // 16*1024*32
  float* Am  = ws + 22220800;   // 20*1024*4
  float* XH  = ws + 22302720;   // 16*1024*784
  float* O0  = ws + 35147776;   // 4*1024*784  (total 38,359,040 floats = 153.4 MB)
  float* outp = (float*)d_out;

  // allow >64KB dynamic LDS for k_seq (ignored/no-op if unsupported)
  (void)hipFuncSetAttribute(reinterpret_cast<const void*>(k_seq),
                            hipFuncAttributeMaxDynamicSharedMemorySize,
                            (PS_COLS + PP_COLS + 832) * 4);

  hipLaunchKernelGGL(k_backbone, dim3(1024), dim3(128), 0, stream,
                     z, sw1,sb1,sw2,sb2, pw1,pb1,pw2,pb2, h2s, h2p);
  hipLaunchKernelGGL(k_params, dim3(164,32), dim3(256), 0, stream,
                     h2s, sw3, sb3, Ps, PS_COLS, 4192, 25872, SOUT);
  hipLaunchKernelGGL(k_params, dim3(166,32), dim3(256), 0, stream,
                     h2p, pw3, pb3, Pp, PP_COLS, 0x7fffffff, 0, POUT);
  hipLaunchKernelGGL(k_seq, dim3(1024), dim3(256), (PS_COLS + PP_COLS + 832)*4, stream,
                     Ps, Pp, Dm, Am);
  hipLaunchKernelGGL(k_xhat, dim3(25,128), dim3(256), 0, stream,
                     h2s, Dm, sw3, sb3, XH);
  hipLaunchKernelGGL(k_out0, dim3((4*BATCH*784 + 255)/256), dim3(256), 0, stream,
                     XH, Am, O0);
  hipLaunchKernelGGL(k_final, dim3((BATCH*784 + 255)/256), dim3(256), 0, stream,
                     O0, Am, outp);
}

// Round 2
// 372.819 us; speedup vs baseline: 1.9318x; 1.9318x over previous
//
#include <hip/hip_runtime.h>
#include <cmath>

#define BATCH 1024
#define SOUT 36336
#define POUT 10596
#define PS_COLS 10464   // s params compacted (dec2 block removed)
#define PP_COLS 10596
#define PD_COLS 25872   // s dec2 block (W 32x784 + b 784)

__device__ __forceinline__ float sigmoidf_(float x){ return 1.0f/(1.0f+__expf(-x)); }
__device__ __forceinline__ float reluf_(float x){ return x>0.0f?x:0.0f; }

// ---------------- K1: backbone hidden h2 (s and p) ----------------
__global__ __launch_bounds__(128) void k_backbone(
    const float* __restrict__ z,
    const float* __restrict__ sw1, const float* __restrict__ sb1,
    const float* __restrict__ sw2, const float* __restrict__ sb2,
    const float* __restrict__ pw1, const float* __restrict__ pb1,
    const float* __restrict__ pw2, const float* __restrict__ pb2,
    float* __restrict__ h2s, float* __restrict__ h2p)
{
  __shared__ float zsh[32];
  __shared__ float h1sh[2][64];
  const int b = blockIdx.x;
  const int tid = threadIdx.x;
  const int g = tid >> 6, o = tid & 63;
  if (tid < 32) zsh[tid] = z[b*32 + tid];
  __syncthreads();
  const float* w1 = g ? pw1 : sw1;
  const float* b1 = g ? pb1 : sb1;
  float acc = b1[o];
  #pragma unroll
  for (int i=0;i<32;i++) acc += zsh[i]*w1[i*64+o];
  h1sh[g][o] = reluf_(acc);
  __syncthreads();
  const float* w2 = g ? pw2 : sw2;
  const float* b2 = g ? pb2 : sb2;
  float acc2 = b2[o];
  #pragma unroll
  for (int i=0;i<64;i++) acc2 += h1sh[g][i]*w2[i*64+o];
  (g ? h2p : h2s)[b*64+o] = reluf_(acc2);
}

// ---------------- K2: params = h2 @ w3 + b3 (column remap, b-tile 128) ----------------
__global__ __launch_bounds__(256) void k_params2(
    const float* __restrict__ h2, const float* __restrict__ w3,
    const float* __restrict__ b3, float* __restrict__ outp,
    int OC, int mapThresh, int mapOff, int srcStride)
{
  __shared__ float wt[64][65];
  __shared__ float h2t[128][64];
  __shared__ float bsh[64];
  const int c0 = blockIdx.x*64, b0 = blockIdx.y*128;
  const int tid = threadIdx.x;
  for (int idx=tid; idx<4096; idx+=256){
    int j = idx >> 6, cc = idx & 63;
    int c = c0 + cc;
    int src = (c < mapThresh) ? c : c + mapOff;
    wt[j][cc] = (c < OC) ? w3[(size_t)j*srcStride + src] : 0.0f;
  }
  if (tid < 64){
    int c = c0 + tid;
    int src = (c < mapThresh) ? c : c + mapOff;
    bsh[tid] = (c < OC) ? b3[src] : 0.0f;
  }
  for (int idx=tid; idx<8192; idx+=256){
    int bb = idx >> 6, j = idx & 63;
    h2t[bb][j] = h2[(size_t)(b0+bb)*64 + j];
  }
  __syncthreads();
  const int cc = tid & 63, bq = tid >> 6;
  const int c = c0 + cc;
  if (c < OC){
    for (int s=0;s<32;s++){
      int bb = bq*32 + s;
      float acc = bsh[cc];
      #pragma unroll
      for (int j=0;j<64;j++) acc += h2t[bb][j]*wt[j][cc];
      outp[(size_t)(b0+bb)*OC + c] = acc;
    }
  }
}

// ---------------- K3: 20 sequential hyper-GRU step pairs, register-resident weights ----
// One block per batch element; tid>>7: 0 = s net, 1 = p net; lt = tid&127.
// Lane roles (per net):
//   lt 0-63 : e1 column (K-half lt>>5) in wA, gru-k col lt in wB, gru-rk col lt in wC
//   lt 64-95: e2 column in wA, gru-k col lt in wB, gru-rk col lt in wC
//   lt 96-127: dec1 column in wA; (p, lt<100) dec2 column in wB
__global__ __launch_bounds__(256, 4) void k_seq(
    const float* __restrict__ Ps, const float* __restrict__ Pp,
    float* __restrict__ Dout, float* __restrict__ Aout)
{
  __shared__ float xvT[64], xvI[64], initZ[64], hst[64];
  __shared__ float psA[128], e2s[64], gxs[192], ghs[128];
  __shared__ float zgs[64], rhs[64], d1s[32];

  const int b = blockIdx.x;
  const int tid = threadIdx.x;
  const int g = tid >> 7, lt = tid & 127;
  const float* Gp = g ? (Pp + (size_t)b*PP_COLS) : (Ps + (size_t)b*PS_COLS);
  const int rnn = g ? 4324 : 4192;

  float wA[32], wB[32], wC[32];
  float bA = 0.f, bB = 0.f;
  {
    int baseA;
    if (lt < 64)       baseA = (lt>>5)*1024 + (lt&31);     // enc1 (64x32), K-half
    else if (lt < 96)  baseA = 2080 + (lt-64);             // enc2 (32x32)
    else               baseA = 3136 + (lt-96);             // dec1 (32x32)
    #pragma unroll
    for (int i=0;i<32;i++) wA[i] = Gp[baseA + i*32];
    if (lt < 32)                 bA = Gp[2048 + lt];
    else if (lt >= 64 && lt < 96) bA = Gp[3104 + (lt-64)];
    else if (lt >= 96)            bA = Gp[4160 + (lt-96)];
    if (lt < 96){
      #pragma unroll
      for (int i=0;i<32;i++) wB[i] = Gp[rnn + i*96 + lt];
      bB = Gp[rnn + 6144 + lt];
      #pragma unroll
      for (int i=0;i<32;i++) wC[i] = Gp[rnn + 3072 + i*96 + lt];
    } else if (g == 1 && lt < 100){
      #pragma unroll
      for (int i=0;i<32;i++) wB[i] = Gp[4192 + i*4 + (lt-96)];
      bB = Gp[4320 + (lt-96)];
    }
  }

  if (tid < 64) hst[tid] = 0.f;
  if (tid < 32) initZ[tid] = Ps[(size_t)b*PS_COLS + 10432 + tid];
  else if (tid < 64) initZ[tid] = Pp[(size_t)b*PP_COLS + 10564 + (tid-32)];
  __syncthreads();
  if (tid < 64) xvT[tid] = initZ[tid];
  __syncthreads();

  auto substep = [&](const float* xv, int aidx, int t16){
    // A: e1 partial sums (split K=64 into two halves)
    if (lt < 64){
      float acc = (lt < 32) ? bA : 0.f;
      const int h32 = (lt >> 5) * 32;
      #pragma unroll
      for (int i=0;i<32;i++) acc += xv[h32+i]*wA[i];
      psA[g*64 + lt] = acc;
    }
    __syncthreads();
    // B: e2 = (relu(e1)) @ Wenc2 + b
    if (lt >= 64 && lt < 96){
      float acc = bA;
      #pragma unroll
      for (int i=0;i<32;i++){
        float e1 = reluf_(psA[g*64+i] + psA[g*64+32+i]);
        acc += e1*wA[i];
      }
      e2s[g*32 + (lt-64)] = acc;
    }
    __syncthreads();
    // C: gx (96 outs) and gh (64 outs, rk cols 0-63 @ old h)
    if (lt < 96){
      float acc = bB;
      #pragma unroll
      for (int i=0;i<32;i++) acc += e2s[g*32+i]*wB[i];
      gxs[g*96 + lt] = acc;
    }
    if (lt < 64){
      float a2 = 0.f;
      #pragma unroll
      for (int i=0;i<32;i++) a2 += hst[g*32+i]*wC[i];
      ghs[g*64 + lt] = a2;
    }
    __syncthreads();
    // D1: gates
    if (lt < 32){
      zgs[g*32+lt] = sigmoidf_(gxs[g*96+lt] + ghs[g*64+lt]);
    } else if (lt < 64){
      int o = lt-32;
      float rg = sigmoidf_(gxs[g*96+32+o] + ghs[g*64+32+o]);
      rhs[g*32+o] = rg * hst[g*32+o];
    }
    __syncthreads();
    // D2: candidate + state update (rk cols 64-95 live on lanes 64-95)
    if (lt >= 64 && lt < 96){
      int o = lt-64;
      float acc = 0.f;
      #pragma unroll
      for (int i=0;i<32;i++) acc += rhs[g*32+i]*wC[i];
      float hh = tanhf(gxs[g*96+64+o] + acc);
      float zv = zgs[g*32+o];
      hst[g*32+o] = zv*hst[g*32+o] + (1.f-zv)*hh;
    }
    __syncthreads();
    // E: dec1
    if (lt >= 96 && (g==1 || t16 >= 0)){
      int o = lt-96;
      float acc = bA;
      #pragma unroll
      for (int i=0;i<32;i++) acc += hst[g*32+i]*wA[i];
      float d = reluf_(acc);
      if (g == 0) Dout[((size_t)t16*BATCH + b)*32 + o] = d;
      else d1s[o] = d;
    }
    __syncthreads();
    // F: p dec2 -> a (runs concurrently with caller's state update)
    if (g == 1 && lt >= 96 && lt < 100){
      int o = lt-96;
      float acc = bB;
      #pragma unroll
      for (int i=0;i<32;i++) acc += d1s[i]*wB[i];
      Aout[((size_t)aidx*BATCH + b)*4 + o] = acc;
    }
  };

  for (int t=0;t<4;t++){
    substep(xvT, t, -1);
    if (tid < 64) xvT[tid] = hst[tid];
    else if (tid < 128) xvI[tid-64] = initZ[tid-64];
    __syncthreads();
    for (int k=0;k<4;k++){
      substep(xvI, 4 + t*4 + k, t*4 + k);
      if (tid < 64) xvI[tid] = hst[tid];
      __syncthreads();
    }
  }
}

// ---------------- bilinear forward sampler (LDS image) ----------------
__device__ __forceinline__ float fetchpix(const float* __restrict__ img, int y, int x){
  if ((unsigned)y >= 28u || (unsigned)x >= 28u) return 0.0f;
  return img[y*28 + x];
}
__device__ __forceinline__ float bilin(const float* __restrict__ img,
                                       float a0, float a1, float a2, float a3,
                                       int r, int c){
  const float stepv = 2.0f/27.0f;
  float gxv = -1.0f + stepv*(float)c;
  float gyv = -1.0f + stepv*(float)r;
  float srcx = (a0 + 1.0f)*gxv + a2;
  float srcy = (a1 + 1.0f)*gyv + a3;
  float px = (srcx + 1.0f)*13.5f;
  float py = (srcy + 1.0f)*13.5f;
  float x0f = floorf(px), y0f = floorf(py);
  float wx = px - x0f, wy = py - y0f;
  int x0 = (int)x0f, y0 = (int)y0f;
  float v00 = fetchpix(img, y0,   x0);
  float v01 = fetchpix(img, y0,   x0+1);
  float v10 = fetchpix(img, y0+1, x0);
  float v11 = fetchpix(img, y0+1, x0+1);
  return v00*(1.0f-wx)*(1.0f-wy) + v01*wx*(1.0f-wy)
       + v10*(1.0f-wx)*wy + v11*wx*wy;
}

// ---------------- K4: fused decode: xhat (streamed from Pd) + both composites ----------
// One block per batch element. LDS holds all 16 xhat images + 4 level-0 images.
__global__ __launch_bounds__(256) void k_dec(
    const float* __restrict__ Pd, const float* __restrict__ Dm,
    const float* __restrict__ Am, float* __restrict__ outp)
{
  extern __shared__ float lds[];
  float* xh = lds;            // 16*784 = 12544
  float* o0 = lds + 12544;    // 4*784  = 3136
  float* Da = lds + 15680;    // 16*33  = 528
  float* av = lds + 16208;    // 80
  const int b = blockIdx.x;
  const int tid = threadIdx.x;

  for (int idx=tid; idx<512; idx+=256){
    int t = idx >> 5, i = idx & 31;
    Da[t*33 + i] = Dm[((size_t)t*BATCH + b)*32 + i];
  }
  if (tid < 16) Da[tid*33 + 32] = 1.0f;
  if (tid < 80) av[tid] = Am[((size_t)(tid>>2)*BATCH + b)*4 + (tid&3)];

  float acc[16][4];
  #pragma unroll
  for (int t=0;t<16;t++){
    acc[t][0]=0.f; acc[t][1]=0.f; acc[t][2]=0.f; acc[t][3]=0.f;
  }
  __syncthreads();

  const float* Pdb = Pd + (size_t)b*PD_COLS;
  for (int i=0;i<33;i++){
    const float* row = Pdb + (i<32 ? i*784 : 25088);
    float v0 = row[tid];
    float v1 = row[tid+256];
    float v2 = (tid < 272) ? row[tid+512] : 0.f;   // 512..783
    float v3 = (tid < 16)  ? row[tid+768] : 0.f;
    #pragma unroll
    for (int t=0;t<16;t++){
      float da = Da[t*33 + i];
      acc[t][0] += da*v0; acc[t][1] += da*v1;
      acc[t][2] += da*v2; acc[t][3] += da*v3;
    }
  }
  #pragma unroll
  for (int t=0;t<16;t++){
    xh[t*784 + tid]       = acc[t][0];
    xh[t*784 + tid + 256] = acc[t][1];
    if (tid < 272) xh[t*784 + tid + 512] = acc[t][2];
    if (tid < 16)  xh[t*784 + tid + 768] = acc[t][3];
  }
  __syncthreads();

  // level-0 composite: o0[t][pix] = sum_k sample(xh[t*4+k], a[4+t*4+k])
  for (int idx=tid; idx<4*784; idx+=256){
    int t = idx / 784, pix = idx - t*784;
    int r = pix / 28, c = pix - r*28;
    float s = 0.f;
    #pragma unroll
    for (int k=0;k<4;k++){
      const float* ap = av + (4 + t*4 + k)*4;
      s += bilin(xh + (t*4+k)*784, ap[0], ap[1], ap[2], ap[3], r, c);
    }
    o0[t*784 + pix] = s;
  }
  __syncthreads();

  // level-1 composite -> d_out
  for (int idx=tid; idx<784; idx+=256){
    int r = idx / 28, c = idx - r*28;
    float s = 0.f;
    #pragma unroll
    for (int t=0;t<4;t++){
      const float* ap = av + t*4;
      s += bilin(o0 + t*784, ap[0], ap[1], ap[2], ap[3], r, c);
    }
    outp[(size_t)b*784 + idx] = s;
  }
}

extern "C" void kernel_launch(void* const* d_in, const int* in_sizes, int n_in,
                              void* d_out, int out_size, void* d_ws, size_t ws_size,
                              hipStream_t stream)
{
  // inputs: x(unused), z, s_w1,s_b1,s_w2,s_b2,s_w3,s_b3, p_w1,p_b1,p_w2,p_b2,p_w3,p_b3
  const float* z   = (const float*)d_in[1];
  const float* sw1 = (const float*)d_in[2];
  const float* sb1 = (const float*)d_in[3];
  const float* sw2 = (const float*)d_in[4];
  const float* sb2 = (const float*)d_in[5];
  const float* sw3 = (const float*)d_in[6];
  const float* sb3 = (const float*)d_in[7];
  const float* pw1 = (const float*)d_in[8];
  const float* pb1 = (const float*)d_in[9];
  const float* pw2 = (const float*)d_in[10];
  const float* pb2 = (const float*)d_in[11];
  const float* pw3 = (const float*)d_in[12];
  const float* pb3 = (const float*)d_in[13];

  float* ws  = (float*)d_ws;
  float* h2s = ws + 0;                       // 65536
  float* h2p = ws + 65536;                   // 65536
  float* Ps  = ws + 131072;                  // 1024*10464 = 10,715,136
  float* Pp  = ws + 131072 + 10715136;       // 1024*10596 = 10,850,304
  // Pd overlays Ps/Pp (they are dead once k_seq finishes; stream-ordered)
  float* Pd  = ws + 131072;                  // 1024*25872 = 26,492,928
  float* Dm  = ws + 131072 + 26492928;       // 16*1024*32 = 524,288
  float* Am  = ws + 131072 + 26492928 + 524288;  // 20*1024*4 = 81,920
  float* outp = (float*)d_out;               // total ws use ~27.2M floats = 109 MB

  (void)hipFuncSetAttribute(reinterpret_cast<const void*>(k_dec),
                            hipFuncAttributeMaxDynamicSharedMemorySize,
                            16288 * 4);

  hipLaunchKernelGGL(k_backbone, dim3(1024), dim3(128), 0, stream,
                     z, sw1,sb1,sw2,sb2, pw1,pb1,pw2,pb2, h2s, h2p);
  hipLaunchKernelGGL(k_params2, dim3(164,8), dim3(256), 0, stream,
                     h2s, sw3, sb3, Ps, PS_COLS, 4192, 25872, SOUT);
  hipLaunchKernelGGL(k_params2, dim3(166,8), dim3(256), 0, stream,
                     h2p, pw3, pb3, Pp, PP_COLS, 0x40000000, 0, POUT);
  hipLaunchKernelGGL(k_seq, dim3(1024), dim3(256), 0, stream,
                     Ps, Pp, Dm, Am);
  hipLaunchKernelGGL(k_params2, dim3(405,8), dim3(256), 0, stream,
                     h2s, sw3, sb3, Pd, PD_COLS, 0, 4192, SOUT);
  hipLaunchKernelGGL(k_dec, dim3(1024), dim3(256), 16288*4, stream,
                     Pd, Dm, Am, outp);
}

// Round 3
// 342.334 us; speedup vs baseline: 2.1038x; 1.0890x over previous
//
#include <hip/hip_runtime.h>
#include <cmath>

#define BATCH 1024
#define SOUT 36336
#define POUT 10596
#define PS_COLS 10464   // s params compacted (dec2 block removed)
#define PP_COLS 10596
#define PD_COLS 25872   // s dec2 block (W 32x784 + b 784)

__device__ __forceinline__ float sigmoidf_(float x){ return 1.0f/(1.0f+__expf(-x)); }
__device__ __forceinline__ float reluf_(float x){ return x>0.0f?x:0.0f; }

// ---------------- K1: backbone hidden h2 (s and p) ----------------
__global__ __launch_bounds__(128) void k_backbone(
    const float* __restrict__ z,
    const float* __restrict__ sw1, const float* __restrict__ sb1,
    const float* __restrict__ sw2, const float* __restrict__ sb2,
    const float* __restrict__ pw1, const float* __restrict__ pb1,
    const float* __restrict__ pw2, const float* __restrict__ pb2,
    float* __restrict__ h2s, float* __restrict__ h2p)
{
  __shared__ float zsh[32];
  __shared__ float h1sh[2][64];
  const int b = blockIdx.x;
  const int tid = threadIdx.x;
  const int g = tid >> 6, o = tid & 63;
  if (tid < 32) zsh[tid] = z[b*32 + tid];
  __syncthreads();
  const float* w1 = g ? pw1 : sw1;
  const float* b1 = g ? pb1 : sb1;
  float acc = b1[o];
  #pragma unroll
  for (int i=0;i<32;i++) acc += zsh[i]*w1[i*64+o];
  h1sh[g][o] = reluf_(acc);
  __syncthreads();
  const float* w2 = g ? pw2 : sw2;
  const float* b2 = g ? pb2 : sb2;
  float acc2 = b2[o];
  #pragma unroll
  for (int i=0;i<64;i++) acc2 += h1sh[g][i]*w2[i*64+o];
  (g ? h2p : h2s)[b*64+o] = reluf_(acc2);
}

// ---------------- K2: register-blocked params GEMM ----------------
// C[b,c] = sum_j h2[b,j]*w3[j,src(c)] + b3[src(c)]
// Tile: 64 b x 128 c, 256 threads = 8 ct x 32 bt; thread: 2 rows x 16 cols.
// Two param-sets (A,B) selected by blockIdx.x range (merged launch).
__global__ __launch_bounds__(256) void k_params3(
    const float* __restrict__ h2A, const float* __restrict__ w3A, const float* __restrict__ b3A,
    float* __restrict__ outA, int OCA, int thrA, int offA, int strideA, int tilesA,
    const float* __restrict__ h2B, const float* __restrict__ w3B, const float* __restrict__ b3B,
    float* __restrict__ outB, int OCB, int thrB, int offB, int strideB)
{
  __shared__ float wt[64][132];   // [k][c] padded, float4-aligned rows
  __shared__ float h2t[64][65];   // [b][k] padded
  __shared__ float bsh[128];
  int xt = blockIdx.x;
  const bool A = (xt < tilesA);
  const float* h2 = A ? h2A : h2B;
  const float* w3 = A ? w3A : w3B;
  const float* b3 = A ? b3A : b3B;
  float* outp     = A ? outA : outB;
  const int OC  = A ? OCA : OCB;
  const int thr = A ? thrA : thrB;
  const int off = A ? offA : offB;
  const int stride = A ? strideA : strideB;
  if (!A) xt -= tilesA;
  const int c0 = xt*128, b0 = blockIdx.y*64;
  const int tid = threadIdx.x;

  for (int idx = tid; idx < 8192; idx += 256){
    int j = idx >> 7, cc = idx & 127;
    int c = c0 + cc;
    int src = (c < thr) ? c : c + off;
    wt[j][cc] = (c < OC) ? w3[(size_t)j*stride + src] : 0.f;
  }
  for (int idx = tid; idx < 4096; idx += 256){
    int bb = idx >> 6, j = idx & 63;
    h2t[bb][j] = h2[(size_t)(b0+bb)*64 + j];
  }
  if (tid < 128){
    int c = c0 + tid;
    int src = (c < thr) ? c : c + off;
    bsh[tid] = (c < OC) ? b3[src] : 0.f;
  }
  __syncthreads();

  const int ct = tid & 7, bt = tid >> 3;
  float acc0[16], acc1[16];
  #pragma unroll
  for (int g=0; g<4; g++){
    #pragma unroll
    for (int e=0; e<4; e++){
      float bv = bsh[ct*4 + g*32 + e];
      acc0[g*4+e] = bv; acc1[g*4+e] = bv;
    }
  }
  #pragma unroll 4
  for (int k=0; k<64; k++){
    const float h0 = h2t[bt*2+0][k];
    const float h1 = h2t[bt*2+1][k];
    #pragma unroll
    for (int g=0; g<4; g++){
      const float4 wv = *reinterpret_cast<const float4*>(&wt[k][ct*4 + g*32]);
      acc0[g*4+0] += h0*wv.x; acc0[g*4+1] += h0*wv.y;
      acc0[g*4+2] += h0*wv.z; acc0[g*4+3] += h0*wv.w;
      acc1[g*4+0] += h1*wv.x; acc1[g*4+1] += h1*wv.y;
      acc1[g*4+2] += h1*wv.z; acc1[g*4+3] += h1*wv.w;
    }
  }
  #pragma unroll
  for (int g=0; g<4; g++){
    const int c = c0 + ct*4 + g*32;
    if (c < OC){
      const int br = b0 + bt*2;
      float4 s0 = make_float4(acc0[g*4+0],acc0[g*4+1],acc0[g*4+2],acc0[g*4+3]);
      float4 s1 = make_float4(acc1[g*4+0],acc1[g*4+1],acc1[g*4+2],acc1[g*4+3]);
      *reinterpret_cast<float4*>(&outp[(size_t)br*OC + c]) = s0;
      *reinterpret_cast<float4*>(&outp[(size_t)(br+1)*OC + c]) = s1;
    }
  }
}

// ---------------- K3: 20 sequential hyper-GRU step pairs, register-resident weights ----
__global__ __launch_bounds__(256, 4) void k_seq(
    const float* __restrict__ Ps, const float* __restrict__ Pp,
    float* __restrict__ Dout, float* __restrict__ Aout)
{
  __shared__ float xvT[64], xvI[64], initZ[64], hst[64];
  __shared__ float psA[128], e2s[64], gxs[192], ghs[128];
  __shared__ float zgs[64], rhs[64], d1s[32];

  const int b = blockIdx.x;
  const int tid = threadIdx.x;
  const int g = tid >> 7, lt = tid & 127;
  const float* Gp = g ? (Pp + (size_t)b*PP_COLS) : (Ps + (size_t)b*PS_COLS);
  const int rnn = g ? 4324 : 4192;

  float wA[32], wB[32], wC[32];
  float bA = 0.f, bB = 0.f;
  {
    int baseA;
    if (lt < 64)       baseA = (lt>>5)*1024 + (lt&31);     // enc1 (64x32), K-half
    else if (lt < 96)  baseA = 2080 + (lt-64);             // enc2 (32x32)
    else               baseA = 3136 + (lt-96);             // dec1 (32x32)
    #pragma unroll
    for (int i=0;i<32;i++) wA[i] = Gp[baseA + i*32];
    if (lt < 32)                 bA = Gp[2048 + lt];
    else if (lt >= 64 && lt < 96) bA = Gp[3104 + (lt-64)];
    else if (lt >= 96)            bA = Gp[4160 + (lt-96)];
    if (lt < 96){
      #pragma unroll
      for (int i=0;i<32;i++) wB[i] = Gp[rnn + i*96 + lt];
      bB = Gp[rnn + 6144 + lt];
      #pragma unroll
      for (int i=0;i<32;i++) wC[i] = Gp[rnn + 3072 + i*96 + lt];
    } else if (g == 1 && lt < 100){
      #pragma unroll
      for (int i=0;i<32;i++) wB[i] = Gp[4192 + i*4 + (lt-96)];
      bB = Gp[4320 + (lt-96)];
    }
  }

  if (tid < 64) hst[tid] = 0.f;
  if (tid < 32) initZ[tid] = Ps[(size_t)b*PS_COLS + 10432 + tid];
  else if (tid < 64) initZ[tid] = Pp[(size_t)b*PP_COLS + 10564 + (tid-32)];
  __syncthreads();
  if (tid < 64) xvT[tid] = initZ[tid];
  __syncthreads();

  auto substep = [&](const float* xv, int aidx, int t16){
    if (lt < 64){
      float acc = (lt < 32) ? bA : 0.f;
      const int h32 = (lt >> 5) * 32;
      #pragma unroll
      for (int i=0;i<32;i++) acc += xv[h32+i]*wA[i];
      psA[g*64 + lt] = acc;
    }
    __syncthreads();
    if (lt >= 64 && lt < 96){
      float acc = bA;
      #pragma unroll
      for (int i=0;i<32;i++){
        float e1 = reluf_(psA[g*64+i] + psA[g*64+32+i]);
        acc += e1*wA[i];
      }
      e2s[g*32 + (lt-64)] = acc;
    }
    __syncthreads();
    if (lt < 96){
      float acc = bB;
      #pragma unroll
      for (int i=0;i<32;i++) acc += e2s[g*32+i]*wB[i];
      gxs[g*96 + lt] = acc;
    }
    if (lt < 64){
      float a2 = 0.f;
      #pragma unroll
      for (int i=0;i<32;i++) a2 += hst[g*32+i]*wC[i];
      ghs[g*64 + lt] = a2;
    }
    __syncthreads();
    if (lt < 32){
      zgs[g*32+lt] = sigmoidf_(gxs[g*96+lt] + ghs[g*64+lt]);
    } else if (lt < 64){
      int o = lt-32;
      float rg = sigmoidf_(gxs[g*96+32+o] + ghs[g*64+32+o]);
      rhs[g*32+o] = rg * hst[g*32+o];
    }
    __syncthreads();
    if (lt >= 64 && lt < 96){
      int o = lt-64;
      float acc = 0.f;
      #pragma unroll
      for (int i=0;i<32;i++) acc += rhs[g*32+i]*wC[i];
      float hh = tanhf(gxs[g*96+64+o] + acc);
      float zv = zgs[g*32+o];
      hst[g*32+o] = zv*hst[g*32+o] + (1.f-zv)*hh;
    }
    __syncthreads();
    if (lt >= 96 && (g==1 || t16 >= 0)){
      int o = lt-96;
      float acc = bA;
      #pragma unroll
      for (int i=0;i<32;i++) acc += hst[g*32+i]*wA[i];
      float d = reluf_(acc);
      if (g == 0) Dout[((size_t)t16*BATCH + b)*32 + o] = d;
      else d1s[o] = d;
    }
    __syncthreads();
    if (g == 1 && lt >= 96 && lt < 100){
      int o = lt-96;
      float acc = bB;
      #pragma unroll
      for (int i=0;i<32;i++) acc += d1s[i]*wB[i];
      Aout[((size_t)aidx*BATCH + b)*4 + o] = acc;
    }
  };

  for (int t=0;t<4;t++){
    substep(xvT, t, -1);
    if (tid < 64) xvT[tid] = hst[tid];
    else if (tid < 128) xvI[tid-64] = initZ[tid-64];
    __syncthreads();
    for (int k=0;k<4;k++){
      substep(xvI, 4 + t*4 + k, t*4 + k);
      if (tid < 64) xvI[tid] = hst[tid];
      __syncthreads();
    }
  }
}

// ---------------- bilinear forward sampler (LDS image) ----------------
__device__ __forceinline__ float fetchpix(const float* __restrict__ img, int y, int x){
  if ((unsigned)y >= 28u || (unsigned)x >= 28u) return 0.0f;
  return img[y*28 + x];
}
__device__ __forceinline__ float bilin(const float* __restrict__ img,
                                       float a0, float a1, float a2, float a3,
                                       int r, int c){
  const float stepv = 2.0f/27.0f;
  float gxv = -1.0f + stepv*(float)c;
  float gyv = -1.0f + stepv*(float)r;
  float srcx = (a0 + 1.0f)*gxv + a2;
  float srcy = (a1 + 1.0f)*gyv + a3;
  float px = (srcx + 1.0f)*13.5f;
  float py = (srcy + 1.0f)*13.5f;
  float x0f = floorf(px), y0f = floorf(py);
  float wx = px - x0f, wy = py - y0f;
  int x0 = (int)x0f, y0 = (int)y0f;
  float v00 = fetchpix(img, y0,   x0);
  float v01 = fetchpix(img, y0,   x0+1);
  float v10 = fetchpix(img, y0+1, x0);
  float v11 = fetchpix(img, y0+1, x0+1);
  return v00*(1.0f-wx)*(1.0f-wy) + v01*wx*(1.0f-wy)
       + v10*(1.0f-wx)*wy + v11*wx*wy;
}

// ---------------- K4: fused decode: xhat (streamed from Pd) + both composites ----------
__global__ __launch_bounds__(256) void k_dec(
    const float* __restrict__ Pd, const float* __restrict__ Dm,
    const float* __restrict__ Am, float* __restrict__ outp)
{
  extern __shared__ float lds[];
  float* xh = lds;            // 16*784 = 12544
  float* o0 = lds + 12544;    // 4*784  = 3136
  float* Da = lds + 15680;    // 16*33  = 528
  float* av = lds + 16208;    // 80
  const int b = blockIdx.x;
  const int tid = threadIdx.x;

  for (int idx=tid; idx<512; idx+=256){
    int t = idx >> 5, i = idx & 31;
    Da[t*33 + i] = Dm[((size_t)t*BATCH + b)*32 + i];
  }
  if (tid < 16) Da[tid*33 + 32] = 1.0f;
  if (tid < 80) av[tid] = Am[((size_t)(tid>>2)*BATCH + b)*4 + (tid&3)];

  float4 acc4[16];
  #pragma unroll
  for (int t=0;t<16;t++) acc4[t] = make_float4(0.f,0.f,0.f,0.f);
  __syncthreads();

  const float* Pdb = Pd + (size_t)b*PD_COLS;
  #pragma unroll 3
  for (int i=0;i<33;i++){
    const float* row = Pdb + (i<32 ? i*784 : 25088);
    float4 v = make_float4(0.f,0.f,0.f,0.f);
    if (tid < 196) v = reinterpret_cast<const float4*>(row)[tid];
    #pragma unroll
    for (int t=0;t<16;t++){
      float da = Da[t*33 + i];
      acc4[t].x += da*v.x; acc4[t].y += da*v.y;
      acc4[t].z += da*v.z; acc4[t].w += da*v.w;
    }
  }
  if (tid < 196){
    #pragma unroll
    for (int t=0;t<16;t++)
      *reinterpret_cast<float4*>(&xh[t*784 + tid*4]) = acc4[t];
  }
  __syncthreads();

  // level-0 composite
  for (int idx=tid; idx<4*784; idx+=256){
    int t = idx / 784, pix = idx - t*784;
    int r = pix / 28, c = pix - r*28;
    float s = 0.f;
    #pragma unroll
    for (int k=0;k<4;k++){
      const float* ap = av + (4 + t*4 + k)*4;
      s += bilin(xh + (t*4+k)*784, ap[0], ap[1], ap[2], ap[3], r, c);
    }
    o0[t*784 + pix] = s;
  }
  __syncthreads();

  // level-1 composite -> d_out
  for (int idx=tid; idx<784; idx+=256){
    int r = idx / 28, c = idx - r*28;
    float s = 0.f;
    #pragma unroll
    for (int t=0;t<4;t++){
      const float* ap = av + t*4;
      s += bilin(o0 + t*784, ap[0], ap[1], ap[2], ap[3], r, c);
    }
    outp[(size_t)b*784 + idx] = s;
  }
}

extern "C" void kernel_launch(void* const* d_in, const int* in_sizes, int n_in,
                              void* d_out, int out_size, void* d_ws, size_t ws_size,
                              hipStream_t stream)
{
  const float* z   = (const float*)d_in[1];
  const float* sw1 = (const float*)d_in[2];
  const float* sb1 = (const float*)d_in[3];
  const float* sw2 = (const float*)d_in[4];
  const float* sb2 = (const float*)d_in[5];
  const float* sw3 = (const float*)d_in[6];
  const float* sb3 = (const float*)d_in[7];
  const float* pw1 = (const float*)d_in[8];
  const float* pb1 = (const float*)d_in[9];
  const float* pw2 = (const float*)d_in[10];
  const float* pb2 = (const float*)d_in[11];
  const float* pw3 = (const float*)d_in[12];
  const float* pb3 = (const float*)d_in[13];

  float* ws  = (float*)d_ws;
  float* h2s = ws + 0;                       // 65536
  float* h2p = ws + 65536;                   // 65536
  float* Ps  = ws + 131072;                  // 1024*10464
  float* Pp  = ws + 131072 + 10715136;       // 1024*10596
  // Pd overlays Ps/Pp (dead after k_seq; stream-ordered)
  float* Pd  = ws + 131072;                  // 1024*25872
  float* Dm  = ws + 131072 + 26492928;       // 16*1024*32
  float* Am  = ws + 131072 + 26492928 + 524288;  // 20*1024*4
  float* outp = (float*)d_out;

  (void)hipFuncSetAttribute(reinterpret_cast<const void*>(k_dec),
                            hipFuncAttributeMaxDynamicSharedMemorySize,
                            16288 * 4);

  hipLaunchKernelGGL(k_backbone, dim3(1024), dim3(128), 0, stream,
                     z, sw1,sb1,sw2,sb2, pw1,pb1,pw2,pb2, h2s, h2p);
  // merged Ps + Pp generation: x-tiles [0,82) -> s, [82,165) -> p
  hipLaunchKernelGGL(k_params3, dim3(165,16), dim3(256), 0, stream,
                     h2s, sw3, sb3, Ps, PS_COLS, 4192, 25872, SOUT, 82,
                     h2p, pw3, pb3, Pp, PP_COLS, 0x40000000, 0, POUT);
  hipLaunchKernelGGL(k_seq, dim3(1024), dim3(256), 0, stream,
                     Ps, Pp, Dm, Am);
  // Pd generation (dec2 slice of s_w3, src col = c + 4192)
  hipLaunchKernelGGL(k_params3, dim3(203,16), dim3(256), 0, stream,
                     h2s, sw3, sb3, Pd, PD_COLS, 0, 4192, SOUT, 203,
                     h2s, sw3, sb3, Pd, PD_COLS, 0, 4192, SOUT);
  hipLaunchKernelGGL(k_dec, dim3(1024), dim3(256), 16288*4, stream,
                     Pd, Dm, Am, outp);
}

// Round 4
// 334.329 us; speedup vs baseline: 2.1542x; 1.0239x over previous
//
#include <hip/hip_runtime.h>
#include <hip/hip_fp16.h>
#include <cmath>

#define BATCH 1024
#define SOUT 36336
#define POUT 10596
#define PS_COLS 10464   // s params compacted (dec2 block removed)
#define PP_COLS 10596
#define PD_COLS 25872   // s dec2 block (W 32x784 + b 784)

__device__ __forceinline__ float sigmoidf_(float x){ return 1.0f/(1.0f+__expf(-x)); }
__device__ __forceinline__ float reluf_(float x){ return x>0.0f?x:0.0f; }

// ---------------- K1: backbone hidden h2 (s and p) ----------------
__global__ __launch_bounds__(128) void k_backbone(
    const float* __restrict__ z,
    const float* __restrict__ sw1, const float* __restrict__ sb1,
    const float* __restrict__ sw2, const float* __restrict__ sb2,
    const float* __restrict__ pw1, const float* __restrict__ pb1,
    const float* __restrict__ pw2, const float* __restrict__ pb2,
    float* __restrict__ h2s, float* __restrict__ h2p)
{
  __shared__ float zsh[32];
  __shared__ float h1sh[2][64];
  const int b = blockIdx.x;
  const int tid = threadIdx.x;
  const int g = tid >> 6, o = tid & 63;
  if (tid < 32) zsh[tid] = z[b*32 + tid];
  __syncthreads();
  const float* w1 = g ? pw1 : sw1;
  const float* b1 = g ? pb1 : sb1;
  float acc = b1[o];
  #pragma unroll
  for (int i=0;i<32;i++) acc += zsh[i]*w1[i*64+o];
  h1sh[g][o] = reluf_(acc);
  __syncthreads();
  const float* w2 = g ? pw2 : sw2;
  const float* b2 = g ? pb2 : sb2;
  float acc2 = b2[o];
  #pragma unroll
  for (int i=0;i<64;i++) acc2 += h1sh[g][i]*w2[i*64+o];
  (g ? h2p : h2s)[b*64+o] = reluf_(acc2);
}

// ---------------- store helpers (fp32 / fp16 output) ----------------
__device__ __forceinline__ void store4v(float* p, const float4& v){
  *reinterpret_cast<float4*>(p) = v;
}
__device__ __forceinline__ void store4v(__half* p, const float4& v){
  reinterpret_cast<__half2*>(p)[0] = __floats2half2_rn(v.x, v.y);
  reinterpret_cast<__half2*>(p)[1] = __floats2half2_rn(v.z, v.w);
}

// ---------------- K2: register-blocked params GEMM, 4x b-tile reuse ----------------
// C[b,c] = sum_j h2[b,j]*w3[j,src(c)] + b3[src(c)]
// Tile: 128 c x (4 x 64 b); 256 threads = 8 ct x 32 bt; thread: 2 rows x 16 cols.
template <typename OT>
__global__ __launch_bounds__(256) void k_params4(
    const float* __restrict__ h2, const float* __restrict__ w3,
    const float* __restrict__ b3, OT* __restrict__ outp,
    int OC, int thr, int off, int stride)
{
  __shared__ float wt[64][132];   // [k][c] padded
  __shared__ float h2t[64][65];   // [b][k] padded
  __shared__ float bsh[128];
  const int c0 = blockIdx.x*128;
  const int tid = threadIdx.x;

  for (int idx = tid; idx < 8192; idx += 256){
    int j = idx >> 7, cc = idx & 127;
    int c = c0 + cc;
    int src = (c < thr) ? c : c + off;
    wt[j][cc] = (c < OC) ? w3[(size_t)j*stride + src] : 0.f;
  }
  if (tid < 128){
    int c = c0 + tid;
    int src = (c < thr) ? c : c + off;
    bsh[tid] = (c < OC) ? b3[src] : 0.f;
  }

  const int ct = tid & 7, bt = tid >> 3;
  for (int sub = 0; sub < 4; ++sub){
    const int b0 = blockIdx.y*256 + sub*64;
    __syncthreads();   // wt ready (sub=0) / previous h2t readers done (sub>0)
    for (int idx = tid; idx < 4096; idx += 256){
      int bb = idx >> 6, j = idx & 63;
      h2t[bb][j] = h2[(size_t)(b0+bb)*64 + j];
    }
    __syncthreads();

    float acc0[16], acc1[16];
    #pragma unroll
    for (int g=0; g<4; g++){
      #pragma unroll
      for (int e=0; e<4; e++){
        float bv = bsh[ct*4 + g*32 + e];
        acc0[g*4+e] = bv; acc1[g*4+e] = bv;
      }
    }
    #pragma unroll 4
    for (int k=0; k<64; k++){
      const float h0 = h2t[bt*2+0][k];
      const float h1 = h2t[bt*2+1][k];
      #pragma unroll
      for (int g=0; g<4; g++){
        const float4 wv = *reinterpret_cast<const float4*>(&wt[k][ct*4 + g*32]);
        acc0[g*4+0] += h0*wv.x; acc0[g*4+1] += h0*wv.y;
        acc0[g*4+2] += h0*wv.z; acc0[g*4+3] += h0*wv.w;
        acc1[g*4+0] += h1*wv.x; acc1[g*4+1] += h1*wv.y;
        acc1[g*4+2] += h1*wv.z; acc1[g*4+3] += h1*wv.w;
      }
    }
    #pragma unroll
    for (int g=0; g<4; g++){
      const int c = c0 + ct*4 + g*32;
      if (c < OC){
        const int br = b0 + bt*2;
        float4 s0 = make_float4(acc0[g*4+0],acc0[g*4+1],acc0[g*4+2],acc0[g*4+3]);
        float4 s1 = make_float4(acc1[g*4+0],acc1[g*4+1],acc1[g*4+2],acc1[g*4+3]);
        store4v(&outp[(size_t)br*OC + c], s0);
        store4v(&outp[(size_t)(br+1)*OC + c], s1);
      }
    }
  }
}

// ---------------- K3: 20 sequential hyper-GRU step pairs ----------------
// Register-resident weights, 4 barriers/substep.
// Net g = tid>>7 (0=s,1=p), lt = tid&127. Per net:
//   lanes 0-63 : e1 K-half psum (wA), gru-k col lt (wB), gru-rk col lt (wC)
//   lanes 64-95: e2 (wA), gru-k xh col (wB), gru-rk cand col (wC), gates+update
//   lanes 96-127: dec1 (wA); (p, lt<100) dec2 (wB)
__global__ __launch_bounds__(256, 3) void k_seq(
    const float* __restrict__ Ps, const float* __restrict__ Pp,
    float* __restrict__ Dout, float* __restrict__ Aout)
{
  __shared__ float xvT[64], xvI[64], initZ[64], hst[64];
  __shared__ float psA[128], e2s[64], gxs[128], ghs[128];
  __shared__ float rhs[64], d1s[32];

  const int b = blockIdx.x;
  const int tid = threadIdx.x;
  const int g = tid >> 7, lt = tid & 127;
  const float* Gp = g ? (Pp + (size_t)b*PP_COLS) : (Ps + (size_t)b*PS_COLS);
  const int rnn = g ? 4324 : 4192;

  float wA[32], wB[32], wC[32];
  float bA = 0.f, bB = 0.f;
  {
    int baseA;
    if (lt < 64)       baseA = (lt>>5)*1024 + (lt&31);     // enc1 (64x32), K-half
    else if (lt < 96)  baseA = 2080 + (lt-64);             // enc2 (32x32)
    else               baseA = 3136 + (lt-96);             // dec1 (32x32)
    #pragma unroll
    for (int i=0;i<32;i++) wA[i] = Gp[baseA + i*32];
    if (lt < 32)                  bA = Gp[2048 + lt];
    else if (lt >= 64 && lt < 96) bA = Gp[3104 + (lt-64)];
    else if (lt >= 96)            bA = Gp[4160 + (lt-96)];
    if (lt < 96){
      #pragma unroll
      for (int i=0;i<32;i++) wB[i] = Gp[rnn + i*96 + lt];
      bB = Gp[rnn + 6144 + lt];
      #pragma unroll
      for (int i=0;i<32;i++) wC[i] = Gp[rnn + 3072 + i*96 + lt];
    } else if (g == 1 && lt < 100){
      #pragma unroll
      for (int i=0;i<32;i++) wB[i] = Gp[4192 + i*4 + (lt-96)];
      bB = Gp[4320 + (lt-96)];
    }
  }

  if (tid < 64) hst[tid] = 0.f;
  if (tid < 32) initZ[tid] = Ps[(size_t)b*PS_COLS + 10432 + tid];
  else if (tid < 64) initZ[tid] = Pp[(size_t)b*PP_COLS + 10564 + (tid-32)];
  __syncthreads();
  if (tid < 64) xvT[tid] = initZ[tid];
  __syncthreads();

  auto substep = [&](const float* xv, int aidx, int t16, bool isTop){
    // A: e1 partial sums (lanes 0-63)
    if (lt < 64){
      float acc = (lt < 32) ? bA : 0.f;
      const int h32 = (lt >> 5) * 32;
      #pragma unroll
      for (int i=0;i<32;i++) acc += xv[h32+i]*wA[i];
      psA[g*64 + lt] = acc;
    }
    __syncthreads();
    // B: e2 = relu(e1) @ Wenc2 + b (lanes 64-95)
    if (lt >= 64 && lt < 96){
      float acc = bA;
      #pragma unroll
      for (int i=0;i<32;i++){
        float e1 = reluf_(psA[g*64+i] + psA[g*64+32+i]);
        acc += e1*wA[i];
      }
      e2s[g*32 + (lt-64)] = acc;
    }
    __syncthreads();
    // C: gx cols 0-63 + gh (lanes 0-63 -> LDS); xh cols 64-95 (lanes 64-95 -> reg)
    float xh = 0.f;
    if (lt < 64){
      float acc = bB, acc2 = 0.f;
      #pragma unroll
      for (int i=0;i<32;i++){
        float e2 = e2s[g*32+i];
        acc  += e2*wB[i];
        acc2 += hst[g*32+i]*wC[i];
      }
      gxs[g*64 + lt] = acc;
      ghs[g*64 + lt] = acc2;
    } else if (lt < 96){
      float acc = bB;
      #pragma unroll
      for (int i=0;i<32;i++) acc += e2s[g*32+i]*wB[i];
      xh = acc;
    }
    __syncthreads();
    // DEF: gates + candidate + h-update (lanes 64-95), then dec1/dec2 (lanes 96-127)
    // -- all producer/consumer pairs live in the same wave: LDS ordering, no barrier.
    if (lt >= 64 && lt < 96){
      int o = lt-64;
      float ho = hst[g*32+o];
      float zg = sigmoidf_(gxs[g*64+o]    + ghs[g*64+o]);
      float rg = sigmoidf_(gxs[g*64+32+o] + ghs[g*64+32+o]);
      rhs[g*32+o] = rg * ho;
      float acc = 0.f;
      #pragma unroll
      for (int i=0;i<32;i++) acc += rhs[g*32+i]*wC[i];
      float hh = tanhf(xh + acc);
      float hn = zg*ho + (1.f-zg)*hh;
      hst[g*32+o] = hn;
      if (isTop) xvT[g*32+o] = hn; else xvI[g*32+o] = hn;
    }
    if (isTop && tid < 64) xvI[tid] = initZ[tid];   // inner loop restarts from inits
    if (lt >= 96 && (g==1 || t16 >= 0)){
      int o = lt-96;
      float acc = bA;
      #pragma unroll
      for (int i=0;i<32;i++) acc += hst[g*32+i]*wA[i];
      float d = reluf_(acc);
      if (g == 0) Dout[((size_t)t16*BATCH + b)*32 + o] = d;
      else d1s[o] = d;
    }
    if (g == 1 && lt >= 96 && lt < 100){
      int o = lt-96;
      float acc = bB;
      #pragma unroll
      for (int i=0;i<32;i++) acc += d1s[i]*wB[i];
      Aout[((size_t)aidx*BATCH + b)*4 + o] = acc;
    }
    __syncthreads();
  };

  for (int t=0;t<4;t++){
    substep(xvT, t, -1, true);
    for (int k=0;k<4;k++){
      substep(xvI, 4 + t*4 + k, t*4 + k, false);
    }
  }
}

// ---------------- bilinear forward sampler (LDS image) ----------------
__device__ __forceinline__ float fetchpix(const float* __restrict__ img, int y, int x){
  if ((unsigned)y >= 28u || (unsigned)x >= 28u) return 0.0f;
  return img[y*28 + x];
}
__device__ __forceinline__ float bilin(const float* __restrict__ img,
                                       float a0, float a1, float a2, float a3,
                                       int r, int c){
  const float stepv = 2.0f/27.0f;
  float gxv = -1.0f + stepv*(float)c;
  float gyv = -1.0f + stepv*(float)r;
  float srcx = (a0 + 1.0f)*gxv + a2;
  float srcy = (a1 + 1.0f)*gyv + a3;
  float px = (srcx + 1.0f)*13.5f;
  float py = (srcy + 1.0f)*13.5f;
  float x0f = floorf(px), y0f = floorf(py);
  float wx = px - x0f, wy = py - y0f;
  int x0 = (int)x0f, y0 = (int)y0f;
  float v00 = fetchpix(img, y0,   x0);
  float v01 = fetchpix(img, y0,   x0+1);
  float v10 = fetchpix(img, y0+1, x0);
  float v11 = fetchpix(img, y0+1, x0+1);
  return v00*(1.0f-wx)*(1.0f-wy) + v01*wx*(1.0f-wy)
       + v10*(1.0f-wx)*wy + v11*wx*wy;
}

// ---------------- K4: fused decode: xhat (fp16 Pd stream) + both composites --------
__global__ __launch_bounds__(256) void k_dec(
    const __half* __restrict__ Pd, const float* __restrict__ Dm,
    const float* __restrict__ Am, float* __restrict__ outp)
{
  extern __shared__ float lds[];
  float* xh = lds;            // 16*784 = 12544
  float* o0 = lds + 12544;    // 4*784  = 3136
  float* Da = lds + 15680;    // 16*33  = 528
  float* av = lds + 16208;    // 80
  const int b = blockIdx.x;
  const int tid = threadIdx.x;

  for (int idx=tid; idx<512; idx+=256){
    int t = idx >> 5, i = idx & 31;
    Da[t*33 + i] = Dm[((size_t)t*BATCH + b)*32 + i];
  }
  if (tid < 16) Da[tid*33 + 32] = 1.0f;
  if (tid < 80) av[tid] = Am[((size_t)(tid>>2)*BATCH + b)*4 + (tid&3)];

  float4 acc4[16];
  #pragma unroll
  for (int t=0;t<16;t++) acc4[t] = make_float4(0.f,0.f,0.f,0.f);
  __syncthreads();

  const __half* Pdb = Pd + (size_t)b*PD_COLS;
  #pragma unroll 3
  for (int i=0;i<33;i++){
    const __half* row = Pdb + (i<32 ? i*784 : 25088);
    float4 v = make_float4(0.f,0.f,0.f,0.f);
    if (tid < 196){
      const __half2 h0 = reinterpret_cast<const __half2*>(row)[tid*2];
      const __half2 h1 = reinterpret_cast<const __half2*>(row)[tid*2+1];
      float2 f0 = __half22float2(h0), f1 = __half22float2(h1);
      v = make_float4(f0.x, f0.y, f1.x, f1.y);
    }
    #pragma unroll
    for (int t=0;t<16;t++){
      float da = Da[t*33 + i];
      acc4[t].x += da*v.x; acc4[t].y += da*v.y;
      acc4[t].z += da*v.z; acc4[t].w += da*v.w;
    }
  }
  if (tid < 196){
    #pragma unroll
    for (int t=0;t<16;t++)
      *reinterpret_cast<float4*>(&xh[t*784 + tid*4]) = acc4[t];
  }
  __syncthreads();

  // level-0 composite
  for (int idx=tid; idx<4*784; idx+=256){
    int t = idx / 784, pix = idx - t*784;
    int r = pix / 28, c = pix - r*28;
    float s = 0.f;
    #pragma unroll
    for (int k=0;k<4;k++){
      const float* ap = av + (4 + t*4 + k)*4;
      s += bilin(xh + (t*4+k)*784, ap[0], ap[1], ap[2], ap[3], r, c);
    }
    o0[t*784 + pix] = s;
  }
  __syncthreads();

  // level-1 composite -> d_out
  for (int idx=tid; idx<784; idx+=256){
    int r = idx / 28, c = idx - r*28;
    float s = 0.f;
    #pragma unroll
    for (int t=0;t<4;t++){
      const float* ap = av + t*4;
      s += bilin(o0 + t*784, ap[0], ap[1], ap[2], ap[3], r, c);
    }
    outp[(size_t)b*784 + idx] = s;
  }
}

extern "C" void kernel_launch(void* const* d_in, const int* in_sizes, int n_in,
                              void* d_out, int out_size, void* d_ws, size_t ws_size,
                              hipStream_t stream)
{
  const float* z   = (const float*)d_in[1];
  const float* sw1 = (const float*)d_in[2];
  const float* sb1 = (const float*)d_in[3];
  const float* sw2 = (const float*)d_in[4];
  const float* sb2 = (const float*)d_in[5];
  const float* sw3 = (const float*)d_in[6];
  const float* sb3 = (const float*)d_in[7];
  const float* pw1 = (const float*)d_in[8];
  const float* pb1 = (const float*)d_in[9];
  const float* pw2 = (const float*)d_in[10];
  const float* pb2 = (const float*)d_in[11];
  const float* pw3 = (const float*)d_in[12];
  const float* pb3 = (const float*)d_in[13];

  float* ws  = (float*)d_ws;
  float*  h2s = ws;                                  // 65536
  float*  h2p = ws + 65536;                          // 65536
  float*  Ps  = ws + 131072;                         // 1024*10464 f32
  float*  Pp  = ws + 131072 + 10715136;              // 1024*10596 f32
  // Pd (fp16) overlays Ps/Pp (dead after k_seq; stream-ordered)
  __half* Pd  = (__half*)(ws + 131072);              // 1024*25872 halfs (13.2M f32 slots)
  float*  Dm  = ws + 131072 + 10715136 + 10850304;   // 16*1024*32
  float*  Am  = Dm + 524288;                         // 20*1024*4
  float*  outp = (float*)d_out;

  (void)hipFuncSetAttribute(reinterpret_cast<const void*>(k_dec),
                            hipFuncAttributeMaxDynamicSharedMemorySize,
                            16288 * 4);

  hipLaunchKernelGGL(k_backbone, dim3(1024), dim3(128), 0, stream,
                     z, sw1,sb1,sw2,sb2, pw1,pb1,pw2,pb2, h2s, h2p);
  hipLaunchKernelGGL((k_params4<float>), dim3(82,4), dim3(256), 0, stream,
                     h2s, sw3, sb3, Ps, PS_COLS, 4192, 25872, SOUT);
  hipLaunchKernelGGL((k_params4<float>), dim3(83,4), dim3(256), 0, stream,
                     h2p, pw3, pb3, Pp, PP_COLS, 0x40000000, 0, POUT);
  hipLaunchKernelGGL(k_seq, dim3(1024), dim3(256), 0, stream,
                     Ps, Pp, Dm, Am);
  hipLaunchKernelGGL((k_params4<__half>), dim3(203,4), dim3(256), 0, stream,
                     h2s, sw3, sb3, Pd, PD_COLS, 0, 4192, SOUT);
  hipLaunchKernelGGL(k_dec, dim3(1024), dim3(256), 16288*4, stream,
                     Pd, Dm, Am, outp);
}